// Round 1
// baseline (553.314 us; speedup 1.0000x reference)
//
#include <hip/hip_runtime.h>
#include <math.h>

#define NN 50000
#define DD 128
#define CC 64
#define EE 800000
#define IND 384

// ---------------- per-node logmap scale factors ----------------
__global__ __launch_bounds__(256) void k_scal(const float* __restrict__ xH,
                                              const float* __restrict__ xS,
                                              float* __restrict__ ch,
                                              float* __restrict__ cs) {
  int gw = (blockIdx.x * 256 + threadIdx.x) >> 6;  // wave id = node
  int lane = threadIdx.x & 63;
  if (gw >= NN) return;
  const float2* h2 = (const float2*)(xH) + (size_t)gw * 64;
  float2 vh = h2[lane];
  float ssh = vh.x * vh.x + vh.y * vh.y;
  if (lane == 0) ssh -= vh.x * vh.x;   // exclude element 0
#pragma unroll
  for (int off = 32; off; off >>= 1) ssh += __shfl_down(ssh, off);
  const float2* s2 = (const float2*)(xS) + (size_t)gw * 64;
  float2 vs = s2[lane];
  float sss = vs.x * vs.x + vs.y * vs.y;
  if (lane == 0) sss -= vs.x * vs.x;
#pragma unroll
  for (int off = 32; off; off >>= 1) sss += __shfl_down(sss, off);
  if (lane == 0) {
    float nrh = sqrtf(ssh);
    float dist = acoshf(fmaxf(vh.x, 1.0f));
    ch[gw] = dist / fmaxf(nrh, 1e-12f);
    float nrs = sqrtf(sss);
    float th = acosf(fminf(fmaxf(vs.x, -1.0f), 1.0f));
    cs[gw] = th / fmaxf(nrs, 1e-12f);
  }
}

// ---------------- edge in-degree count ----------------
__global__ __launch_bounds__(256) void k_count(const int* __restrict__ dst,
                                               int* __restrict__ cnt) {
  int e = blockIdx.x * 256 + threadIdx.x;
  if (e < EE) atomicAdd(&cnt[dst[e]], 1);
}

// ---------------- exclusive scan (single block, wave-shfl) ----------------
__global__ __launch_bounds__(1024) void k_scan(const int* __restrict__ cnt,
                                               int* __restrict__ rowstart,
                                               int* __restrict__ cursor,
                                               float* __restrict__ dinv) {
  __shared__ int wsum[16];
  __shared__ int carry_s;
  int tid = threadIdx.x;
  int wave = tid >> 6, lane = tid & 63;
  if (tid == 0) carry_s = 0;
  __syncthreads();
  for (int base = 0; base < NN; base += 1024) {
    int i = base + tid;
    int v = (i < NN) ? cnt[i] : 0;
    int x = v;  // inclusive wave scan
#pragma unroll
    for (int off = 1; off < 64; off <<= 1) {
      int t = __shfl_up(x, off);
      if (lane >= off) x += t;
    }
    if (lane == 63) wsum[wave] = x;
    __syncthreads();
    if (wave == 0 && lane < 16) {
      int y = wsum[lane];
#pragma unroll
      for (int off = 1; off < 16; off <<= 1) {
        int t = __shfl_up(y, off);
        if (lane >= off) y += t;
      }
      wsum[lane] = y;  // inclusive wave totals
    }
    __syncthreads();
    int wave_excl = (wave == 0) ? 0 : wsum[wave - 1];
    int carry = carry_s;
    if (i < NN) {
      int ex = carry + wave_excl + x - v;
      rowstart[i] = ex;
      cursor[i] = ex;
      dinv[i] = 1.0f / sqrtf((float)(v + 1));  // +1 self loop
    }
    __syncthreads();
    if (tid == 1023) carry_s = carry + wsum[15];
    __syncthreads();
  }
  if (tid == 0) rowstart[NN] = carry_s;
}

// ---------------- CSR placement ----------------
__global__ __launch_bounds__(256) void k_place(const int* __restrict__ src,
                                               const int* __restrict__ dst,
                                               int* __restrict__ cursor,
                                               int* __restrict__ col) {
  int e = blockIdx.x * 256 + threadIdx.x;
  if (e < EE) {
    int d = dst[e];
    int p = atomicAdd(&cursor[d], 1);
    col[p] = src[e];
  }
}

// ---------------- fused logmap-concat GEMM: h = x @ W ----------------
__global__ __launch_bounds__(256) void k_gemm(const float* __restrict__ xE,
                                              const float* __restrict__ xH,
                                              const float* __restrict__ xS,
                                              const float* __restrict__ ch,
                                              const float* __restrict__ cs,
                                              const float* __restrict__ W,
                                              float* __restrict__ h) {
  __shared__ float As[64][33];   // [node][k] padded
  __shared__ float Bs[32][DD];   // [k][col]
  int tid = threadIdx.x;
  int tx = tid & 15;   // node group: nodes tx*4..+3
  int ty = tid >> 4;   // col group : cols ty*8..+7
  int m0 = blockIdx.x * 64;
  float acc[4][8];
#pragma unroll
  for (int j = 0; j < 4; ++j)
#pragma unroll
    for (int n = 0; n < 8; ++n) acc[j][n] = 0.f;

  for (int kb = 0; kb < IND; kb += 32) {
#pragma unroll
    for (int it = 0; it < 8; ++it) {       // A tile: 64x32
      int idx = tid + it * 256;
      int m = idx >> 5, k = idx & 31;
      int node = m0 + m;
      int gc = kb + k;
      float v = 0.f;
      if (node < NN) {
        if (gc < DD) v = xE[(size_t)node * DD + gc];
        else if (gc < 2 * DD) {
          int r = gc - DD;
          v = r ? ch[node] * xH[(size_t)node * DD + r] : 0.f;
        } else {
          int r = gc - 2 * DD;
          v = r ? cs[node] * xS[(size_t)node * DD + r] : 0.f;
        }
      }
      As[m][k] = v;
    }
#pragma unroll
    for (int it = 0; it < 16; ++it) {      // B tile: 32x128
      int idx = tid + it * 256;
      int k = idx >> 7, n = idx & 127;
      Bs[k][n] = W[(size_t)(kb + k) * DD + n];
    }
    __syncthreads();
#pragma unroll
    for (int k = 0; k < 32; ++k) {
      float a[4];
#pragma unroll
      for (int j = 0; j < 4; ++j) a[j] = As[tx * 4 + j][k];
      float b[8];
      *(float4*)&b[0] = *(const float4*)&Bs[k][ty * 8];
      *(float4*)&b[4] = *(const float4*)&Bs[k][ty * 8 + 4];
#pragma unroll
      for (int j = 0; j < 4; ++j)
#pragma unroll
        for (int n = 0; n < 8; ++n) acc[j][n] += a[j] * b[n];
    }
    __syncthreads();
  }
#pragma unroll
  for (int j = 0; j < 4; ++j) {
    int node = m0 + tx * 4 + j;
    if (node < NN) {
      *(float4*)&h[(size_t)node * DD + ty * 8] =
          make_float4(acc[j][0], acc[j][1], acc[j][2], acc[j][3]);
      *(float4*)&h[(size_t)node * DD + ty * 8 + 4] =
          make_float4(acc[j][4], acc[j][5], acc[j][6], acc[j][7]);
    }
  }
}

// ---------------- normalize class embeddings ----------------
__global__ __launch_bounds__(256) void k_clsn(const float* __restrict__ cls,
                                              float* __restrict__ clsn) {
  int wave = threadIdx.x >> 6, lane = threadIdx.x & 63;
  for (int c = wave; c < CC; c += 4) {
    const float2* r2 = (const float2*)(cls + (size_t)c * DD);
    float2 v = r2[lane];
    float ss = v.x * v.x + v.y * v.y;
#pragma unroll
    for (int off = 32; off; off >>= 1) ss += __shfl_down(ss, off);
    ss = __shfl(ss, 0);
    float inv = 1.0f / fmaxf(sqrtf(ss), 1e-8f);
    float2 o;
    o.x = v.x * inv;
    o.y = v.y * inv;
    ((float2*)(clsn + (size_t)c * DD))[lane] = o;
  }
}

// ---------------- CSR aggregation: xg = D^-1/2 A D^-1/2 h + b ----------------
__global__ __launch_bounds__(256) void k_agg(const float* __restrict__ h,
                                             const int* __restrict__ rowstart,
                                             const int* __restrict__ col,
                                             const float* __restrict__ dinv,
                                             const float* __restrict__ b,
                                             float* __restrict__ xg) {
  int w = (blockIdx.x * 256 + threadIdx.x) >> 6;  // wave id = node
  int lane = threadIdx.x & 63;
  if (w >= NN) return;
  const float2* h2 = (const float2*)h;
  float dv = dinv[w];
  float2 hv = h2[(size_t)w * 64 + lane];
  float ax = dv * hv.x, ay = dv * hv.y;  // self loop (outer dv applied at end)
  int s = rowstart[w], e = rowstart[w + 1];
  for (int j = s; j < e; ++j) {
    int srcn = col[j];
    float f = dinv[srcn];
    float2 v = h2[(size_t)srcn * 64 + lane];
    ax += f * v.x;
    ay += f * v.y;
  }
  const float2* b2 = (const float2*)b;
  float2 bb = b2[lane];
  float2 o;
  o.x = dv * ax + bb.x;
  o.y = dv * ay + bb.y;
  ((float2*)xg)[(size_t)w * 64 + lane] = o;
}

// ---------------- row-normalize + classifier dot ----------------
__global__ __launch_bounds__(256) void k_out(const float* __restrict__ xg,
                                             const float* __restrict__ clsn,
                                             float* __restrict__ out) {
  __shared__ float4 cls4[CC * 32];   // XOR-swizzled on float4 index
  __shared__ float4 xrow[4][32];
  int tid = threadIdx.x;
  for (int idx = tid; idx < CC * 32; idx += 256) {
    int c = idx >> 5, f4 = idx & 31;
    float4 v = ((const float4*)clsn)[(size_t)c * 32 + f4];
    cls4[c * 32 + (f4 ^ (c & 7))] = v;
  }
  __syncthreads();
  int wave = tid >> 6, lane = tid & 63;
  int node = blockIdx.x * 4 + wave;
  if (node < NN) {
    const float2* x2 = (const float2*)xg;
    float2 v = x2[(size_t)node * 64 + lane];
    float ss = v.x * v.x + v.y * v.y;
#pragma unroll
    for (int off = 32; off; off >>= 1) ss += __shfl_xor(ss, off);
    float inv = 1.0f / fmaxf(sqrtf(ss), 1e-8f);
    float2 o;
    o.x = v.x * inv;
    o.y = v.y * inv;
    ((float2*)&xrow[wave][0])[lane] = o;
    float accv = 0.f;
    int c = lane;
#pragma unroll
    for (int f4 = 0; f4 < 32; ++f4) {
      float4 xv = xrow[wave][f4];                    // broadcast
      float4 cv = cls4[c * 32 + (f4 ^ (c & 7))];     // conflict-free
      accv += xv.x * cv.x + xv.y * cv.y + xv.z * cv.z + xv.w * cv.w;
    }
    out[(size_t)node * CC + c] = accv;
  }
}

extern "C" void kernel_launch(void* const* d_in, const int* in_sizes, int n_in,
                              void* d_out, int out_size, void* d_ws, size_t ws_size,
                              hipStream_t stream) {
  const float* xE = (const float*)d_in[0];
  const float* xH = (const float*)d_in[1];
  const float* xS = (const float*)d_in[2];
  const int* ei = (const int*)d_in[3];
  const float* W = (const float*)d_in[4];
  const float* b = (const float*)d_in[5];
  const float* cls = (const float*)d_in[6];
  float* out = (float*)d_out;

  char* ws = (char*)d_ws;
  size_t off = 0;
  auto alloc = [&](size_t bytes) {
    void* p = ws + off;
    off = (off + bytes + 255) & ~(size_t)255;
    return p;
  };
  float* h = (float*)alloc((size_t)NN * DD * 4);
  float* xg = (float*)alloc((size_t)NN * DD * 4);
  float* dinv = (float*)alloc((size_t)NN * 4);
  float* chv = (float*)alloc((size_t)NN * 4);
  float* csv = (float*)alloc((size_t)NN * 4);
  int* cnt = (int*)alloc((size_t)NN * 4);
  int* rowst = (int*)alloc((size_t)(NN + 1) * 4);
  int* cursor = (int*)alloc((size_t)NN * 4);
  int* col = (int*)alloc((size_t)EE * 4);
  float* clsn = (float*)alloc((size_t)CC * DD * 4);

  const int* esrc = ei;
  const int* edst = ei + EE;

  hipMemsetAsync(cnt, 0, (size_t)NN * 4, stream);
  k_scal<<<(NN + 3) / 4, 256, 0, stream>>>(xH, xS, chv, csv);
  k_count<<<(EE + 255) / 256, 256, 0, stream>>>(edst, cnt);
  k_scan<<<1, 1024, 0, stream>>>(cnt, rowst, cursor, dinv);
  k_place<<<(EE + 255) / 256, 256, 0, stream>>>(esrc, edst, cursor, col);
  k_gemm<<<(NN + 63) / 64, 256, 0, stream>>>(xE, xH, xS, chv, csv, W, h);
  k_clsn<<<1, 256, 0, stream>>>(cls, clsn);
  k_agg<<<(NN + 3) / 4, 256, 0, stream>>>(h, rowst, col, dinv, b, xg);
  k_out<<<(NN + 3) / 4, 256, 0, stream>>>(xg, clsn, out);
}

// Round 2
// 331.459 us; speedup vs baseline: 1.6693x; 1.6693x over previous
//
#include <hip/hip_runtime.h>
#include <hip/hip_bf16.h>
#include <math.h>

#define NN 50000
#define DD 128
#define CC 64
#define EE 800000
#define IND 384

typedef __attribute__((ext_vector_type(8))) short s8v;
typedef __attribute__((ext_vector_type(4))) float f4v;

static __device__ __forceinline__ unsigned short f2bf(float f) {
  __hip_bfloat16 b = __float2bfloat16(f);
  return *reinterpret_cast<unsigned short*>(&b);
}
static __device__ __forceinline__ float bf2f(unsigned short u) {
  __hip_bfloat16 b = *reinterpret_cast<__hip_bfloat16*>(&u);
  return __bfloat162float(b);
}

// ---------------- per-node logmap scale factors ----------------
__global__ __launch_bounds__(256) void k_scal(const float* __restrict__ xH,
                                              const float* __restrict__ xS,
                                              float* __restrict__ ch,
                                              float* __restrict__ cs) {
  int gw = (blockIdx.x * 256 + threadIdx.x) >> 6;
  int lane = threadIdx.x & 63;
  if (gw >= NN) return;
  const float2* h2 = (const float2*)(xH) + (size_t)gw * 64;
  float2 vh = h2[lane];
  float ssh = vh.x * vh.x + vh.y * vh.y;
  if (lane == 0) ssh -= vh.x * vh.x;
#pragma unroll
  for (int off = 32; off; off >>= 1) ssh += __shfl_down(ssh, off);
  const float2* s2 = (const float2*)(xS) + (size_t)gw * 64;
  float2 vs = s2[lane];
  float sss = vs.x * vs.x + vs.y * vs.y;
  if (lane == 0) sss -= vs.x * vs.x;
#pragma unroll
  for (int off = 32; off; off >>= 1) sss += __shfl_down(sss, off);
  if (lane == 0) {
    float nrh = sqrtf(ssh);
    float dist = acoshf(fmaxf(vh.x, 1.0f));
    ch[gw] = dist / fmaxf(nrh, 1e-12f);
    float nrs = sqrtf(sss);
    float th = acosf(fminf(fmaxf(vs.x, -1.0f), 1.0f));
    cs[gw] = th / fmaxf(nrs, 1e-12f);
  }
}

// ---------------- edge in-degree count ----------------
__global__ __launch_bounds__(256) void k_count(const int* __restrict__ dst,
                                               int* __restrict__ cnt) {
  int e = blockIdx.x * 256 + threadIdx.x;
  if (e < EE) atomicAdd(&cnt[dst[e]], 1);
}

// ---------------- hierarchical exclusive scan ----------------
__global__ __launch_bounds__(1024) void k_scan1(const int* __restrict__ cnt,
                                                int* __restrict__ rowstart,
                                                float* __restrict__ dinv,
                                                int* __restrict__ bsum) {
  __shared__ int wsum[16];
  int tid = threadIdx.x;
  int wave = tid >> 6, lane = tid & 63;
  int i = blockIdx.x * 1024 + tid;
  int v = (i < NN) ? cnt[i] : 0;
  int x = v;
#pragma unroll
  for (int off = 1; off < 64; off <<= 1) {
    int t = __shfl_up(x, off);
    if (lane >= off) x += t;
  }
  if (lane == 63) wsum[wave] = x;
  __syncthreads();
  if (wave == 0 && lane < 16) {
    int y = wsum[lane];
#pragma unroll
    for (int off = 1; off < 16; off <<= 1) {
      int t = __shfl_up(y, off);
      if (lane >= off) y += t;
    }
    wsum[lane] = y;
  }
  __syncthreads();
  int ex = (wave ? wsum[wave - 1] : 0) + x - v;
  if (i < NN) {
    rowstart[i] = ex;
    dinv[i] = 1.0f / sqrtf((float)(v + 1));
  }
  if (tid == 1023) bsum[blockIdx.x] = wsum[15];
}

__global__ __launch_bounds__(64) void k_scan2(int* __restrict__ bsum,
                                              int* __restrict__ rowstart,
                                              int nb) {
  int lane = threadIdx.x;
  int v = (lane < nb) ? bsum[lane] : 0;
  int x = v;
#pragma unroll
  for (int off = 1; off < 64; off <<= 1) {
    int t = __shfl_up(x, off);
    if (lane >= off) x += t;
  }
  if (lane < nb) bsum[lane] = x - v;
  if (lane == 0) rowstart[NN] = EE;
}

__global__ __launch_bounds__(1024) void k_scan3(int* __restrict__ rowstart,
                                                int* __restrict__ cursor,
                                                const int* __restrict__ bsum) {
  int i = blockIdx.x * 1024 + threadIdx.x;
  if (i < NN) {
    int r = rowstart[i] + bsum[blockIdx.x];
    rowstart[i] = r;
    cursor[i] = r;
  }
}

// ---------------- CSR placement ----------------
__global__ __launch_bounds__(256) void k_place(const int* __restrict__ src,
                                               const int* __restrict__ dst,
                                               int* __restrict__ cursor,
                                               int* __restrict__ col) {
  int e = blockIdx.x * 256 + threadIdx.x;
  if (e < EE) {
    int d = dst[e];
    int p = atomicAdd(&cursor[d], 1);
    col[p] = src[e];
  }
}

// ---------------- W transpose + bf16 hi/lo split: Wt[128][384] ----------------
__global__ __launch_bounds__(256) void k_wprep(const float* __restrict__ W,
                                               unsigned short* __restrict__ Wth,
                                               unsigned short* __restrict__ Wtl) {
  int flat = blockIdx.x * 256 + threadIdx.x;  // 49152 total
  if (flat >= IND * DD) return;
  int n = flat / IND;
  int k = flat - n * IND;
  float v = W[(size_t)k * DD + n];
  unsigned short hi = f2bf(v);
  unsigned short lo = f2bf(v - bf2f(hi));
  Wth[(size_t)n * IND + k] = hi;
  Wtl[(size_t)n * IND + k] = lo;
}

// ---------------- MFMA GEMM: h = [xE | ch*xH | cs*xS] @ W (hi/lo split) ----
// block: 64 rows x 128 cols, 4 waves (2x2), wave = 32 rows x 64 cols
__global__ __launch_bounds__(256) void k_gemm(const float* __restrict__ xE,
                                              const float* __restrict__ xH,
                                              const float* __restrict__ xS,
                                              const float* __restrict__ ch,
                                              const float* __restrict__ cs,
                                              const unsigned short* __restrict__ Wth,
                                              const unsigned short* __restrict__ Wtl,
                                              float* __restrict__ h) {
  __shared__ unsigned short Ah[64 * 64];
  __shared__ unsigned short Al[64 * 64];
  int tid = threadIdx.x;
  int lane = tid & 63;
  int wid = tid >> 6;
  int wr = wid >> 1, wc = wid & 1;
  int r0 = wr * 32, c0 = wc * 64;
  int bm0 = blockIdx.x * 64;

  f4v acc[2][4];
#pragma unroll
  for (int m = 0; m < 2; ++m)
#pragma unroll
    for (int nf = 0; nf < 4; ++nf) acc[m][nf] = f4v{0.f, 0.f, 0.f, 0.f};

  int l15 = lane & 15;
  int lhi = lane >> 4;

  for (int kb = 0; kb < IND; kb += 64) {
    int sec = kb >> 7;          // 0:E 1:H 2:S
    int off = kb & 127;
    const float* src = (sec == 0) ? xE : (sec == 1) ? xH : xS;
    // ---- stage A tile 64x64 with fused scale + hi/lo split ----
#pragma unroll
    for (int it = 0; it < 4; ++it) {
      int flat = tid + it * 256;
      int row = flat >> 4;       // 0..63
      int f4 = flat & 15;        // 16B chunk in row
      int node = bm0 + row;
      float4 v = make_float4(0.f, 0.f, 0.f, 0.f);
      float scale = 0.f;
      if (node < NN) {
        v = *(const float4*)&src[(size_t)node * DD + off + f4 * 4];
        scale = (sec == 0) ? 1.0f : (sec == 1) ? ch[node] : cs[node];
      }
      v.x *= scale; v.y *= scale; v.z *= scale; v.w *= scale;
      if (sec > 0 && off == 0 && f4 == 0) v.x = 0.f;  // logmap zero column
      ushort4 hi, lo;
      hi.x = f2bf(v.x); lo.x = f2bf(v.x - bf2f(hi.x));
      hi.y = f2bf(v.y); lo.y = f2bf(v.y - bf2f(hi.y));
      hi.z = f2bf(v.z); lo.z = f2bf(v.z - bf2f(hi.z));
      hi.w = f2bf(v.w); lo.w = f2bf(v.w - bf2f(hi.w));
      int idx = (row * 64 + f4 * 4) ^ ((row & 7) << 3);  // ushort units, XOR swizzle
      *(ushort4*)&Ah[idx] = hi;
      *(ushort4*)&Al[idx] = lo;
    }
    __syncthreads();
    // ---- two K=32 MFMA steps ----
#pragma unroll
    for (int ks = 0; ks < 2; ++ks) {
      s8v ahi[2], alo[2];
#pragma unroll
      for (int m = 0; m < 2; ++m) {
        int row = r0 + m * 16 + l15;
        int idx = (row * 64 + ks * 32 + lhi * 8) ^ ((row & 7) << 3);
        ahi[m] = *reinterpret_cast<const s8v*>(&Ah[idx]);
        alo[m] = *reinterpret_cast<const s8v*>(&Al[idx]);
      }
#pragma unroll
      for (int nf = 0; nf < 4; ++nf) {
        int n = c0 + nf * 16 + l15;
        int kk = kb + ks * 32 + lhi * 8;
        s8v bhi = *reinterpret_cast<const s8v*>(&Wth[(size_t)n * IND + kk]);
        s8v blo = *reinterpret_cast<const s8v*>(&Wtl[(size_t)n * IND + kk]);
#pragma unroll
        for (int m = 0; m < 2; ++m) {
          acc[m][nf] = __builtin_amdgcn_mfma_f32_16x16x32_bf16(ahi[m], bhi, acc[m][nf], 0, 0, 0);
          acc[m][nf] = __builtin_amdgcn_mfma_f32_16x16x32_bf16(alo[m], bhi, acc[m][nf], 0, 0, 0);
          acc[m][nf] = __builtin_amdgcn_mfma_f32_16x16x32_bf16(ahi[m], blo, acc[m][nf], 0, 0, 0);
        }
      }
    }
    __syncthreads();
  }
  // ---- epilogue: C layout col=lane&15, row=(lane>>4)*4+j ----
#pragma unroll
  for (int m = 0; m < 2; ++m)
#pragma unroll
    for (int nf = 0; nf < 4; ++nf) {
      int colx = c0 + nf * 16 + l15;
      int rowb = bm0 + r0 + m * 16 + lhi * 4;
#pragma unroll
      for (int j = 0; j < 4; ++j) {
        int node = rowb + j;
        if (node < NN) h[(size_t)node * DD + colx] = acc[m][nf][j];
      }
    }
}

// ---------------- normalize class embeddings ----------------
__global__ __launch_bounds__(256) void k_clsn(const float* __restrict__ cls,
                                              float* __restrict__ clsn) {
  int wave = threadIdx.x >> 6, lane = threadIdx.x & 63;
  for (int c = wave; c < CC; c += 4) {
    const float2* r2 = (const float2*)(cls + (size_t)c * DD);
    float2 v = r2[lane];
    float ss = v.x * v.x + v.y * v.y;
#pragma unroll
    for (int off = 32; off; off >>= 1) ss += __shfl_down(ss, off);
    ss = __shfl(ss, 0);
    float inv = 1.0f / fmaxf(sqrtf(ss), 1e-8f);
    float2 o;
    o.x = v.x * inv;
    o.y = v.y * inv;
    ((float2*)(clsn + (size_t)c * DD))[lane] = o;
  }
}

// ---------------- CSR aggregation ----------------
__global__ __launch_bounds__(256) void k_agg(const float* __restrict__ h,
                                             const int* __restrict__ rowstart,
                                             const int* __restrict__ col,
                                             const float* __restrict__ dinv,
                                             const float* __restrict__ b,
                                             float* __restrict__ xg) {
  int w = (blockIdx.x * 256 + threadIdx.x) >> 6;
  int lane = threadIdx.x & 63;
  if (w >= NN) return;
  const float2* h2 = (const float2*)h;
  float dv = dinv[w];
  float2 hv = h2[(size_t)w * 64 + lane];
  float ax = dv * hv.x, ay = dv * hv.y;
  int s = rowstart[w], e = rowstart[w + 1];
  for (int j = s; j < e; ++j) {
    int srcn = col[j];
    float f = dinv[srcn];
    float2 v = h2[(size_t)srcn * 64 + lane];
    ax += f * v.x;
    ay += f * v.y;
  }
  const float2* b2 = (const float2*)b;
  float2 bb = b2[lane];
  float2 o;
  o.x = dv * ax + bb.x;
  o.y = dv * ay + bb.y;
  ((float2*)xg)[(size_t)w * 64 + lane] = o;
}

// ---------------- row-normalize + classifier dot ----------------
__global__ __launch_bounds__(256) void k_out(const float* __restrict__ xg,
                                             const float* __restrict__ clsn,
                                             float* __restrict__ out) {
  __shared__ float4 cls4[CC * 32];
  __shared__ float4 xrow[4][32];
  int tid = threadIdx.x;
  for (int idx = tid; idx < CC * 32; idx += 256) {
    int c = idx >> 5, f4 = idx & 31;
    float4 v = ((const float4*)clsn)[(size_t)c * 32 + f4];
    cls4[c * 32 + (f4 ^ (c & 7))] = v;
  }
  __syncthreads();
  int wave = tid >> 6, lane = tid & 63;
  int node = blockIdx.x * 4 + wave;
  if (node < NN) {
    const float2* x2 = (const float2*)xg;
    float2 v = x2[(size_t)node * 64 + lane];
    float ss = v.x * v.x + v.y * v.y;
#pragma unroll
    for (int off = 32; off; off >>= 1) ss += __shfl_xor(ss, off);
    float inv = 1.0f / fmaxf(sqrtf(ss), 1e-8f);
    float2 o;
    o.x = v.x * inv;
    o.y = v.y * inv;
    ((float2*)&xrow[wave][0])[lane] = o;
    float accv = 0.f;
    int c = lane;
#pragma unroll
    for (int f4 = 0; f4 < 32; ++f4) {
      float4 xv = xrow[wave][f4];
      float4 cv = cls4[c * 32 + (f4 ^ (c & 7))];
      accv += xv.x * cv.x + xv.y * cv.y + xv.z * cv.z + xv.w * cv.w;
    }
    out[(size_t)node * CC + c] = accv;
  }
}

extern "C" void kernel_launch(void* const* d_in, const int* in_sizes, int n_in,
                              void* d_out, int out_size, void* d_ws, size_t ws_size,
                              hipStream_t stream) {
  const float* xE = (const float*)d_in[0];
  const float* xH = (const float*)d_in[1];
  const float* xS = (const float*)d_in[2];
  const int* ei = (const int*)d_in[3];
  const float* W = (const float*)d_in[4];
  const float* b = (const float*)d_in[5];
  const float* cls = (const float*)d_in[6];
  float* out = (float*)d_out;

  char* ws = (char*)d_ws;
  size_t off = 0;
  auto alloc = [&](size_t bytes) {
    void* p = ws + off;
    off = (off + bytes + 255) & ~(size_t)255;
    return p;
  };
  float* h = (float*)alloc((size_t)NN * DD * 4);
  float* xg = (float*)alloc((size_t)NN * DD * 4);
  float* dinv = (float*)alloc((size_t)NN * 4);
  float* chv = (float*)alloc((size_t)NN * 4);
  float* csv = (float*)alloc((size_t)NN * 4);
  int* cnt = (int*)alloc((size_t)NN * 4);
  int* rowst = (int*)alloc((size_t)(NN + 1) * 4);
  int* cursor = (int*)alloc((size_t)NN * 4);
  int* col = (int*)alloc((size_t)EE * 4);
  float* clsn = (float*)alloc((size_t)CC * DD * 4);
  unsigned short* Wth = (unsigned short*)alloc((size_t)DD * IND * 2);
  unsigned short* Wtl = (unsigned short*)alloc((size_t)DD * IND * 2);
  int* bsum = (int*)alloc(64 * 4);

  const int* esrc = ei;
  const int* edst = ei + EE;
  const int NB = (NN + 1023) / 1024;  // 49

  hipMemsetAsync(cnt, 0, (size_t)NN * 4, stream);
  k_scal<<<(NN + 3) / 4, 256, 0, stream>>>(xH, xS, chv, csv);
  k_count<<<(EE + 255) / 256, 256, 0, stream>>>(edst, cnt);
  k_scan1<<<NB, 1024, 0, stream>>>(cnt, rowst, dinv, bsum);
  k_scan2<<<1, 64, 0, stream>>>(bsum, rowst, NB);
  k_scan3<<<NB, 1024, 0, stream>>>(rowst, cursor, bsum);
  k_place<<<(EE + 255) / 256, 256, 0, stream>>>(esrc, edst, cursor, col);
  k_wprep<<<(IND * DD + 255) / 256, 256, 0, stream>>>(W, Wth, Wtl);
  k_gemm<<<(NN + 63) / 64, 256, 0, stream>>>(xE, xH, xS, chv, csv, Wth, Wtl, h);
  k_clsn<<<1, 256, 0, stream>>>(cls, clsn);
  k_agg<<<(NN + 3) / 4, 256, 0, stream>>>(h, rowst, col, dinv, b, xg);
  k_out<<<(NN + 3) / 4, 256, 0, stream>>>(xg, clsn, out);
}

// Round 3
// 286.605 us; speedup vs baseline: 1.9306x; 1.1565x over previous
//
#include <hip/hip_runtime.h>
#include <hip/hip_bf16.h>
#include <math.h>

#define NN 50000
#define DD 128
#define CC 64
#define EE 800000
#define IND 384

typedef __attribute__((ext_vector_type(8))) short s8v;
typedef __attribute__((ext_vector_type(4))) float f4v;

static __device__ __forceinline__ unsigned short f2bf(float f) {
  __hip_bfloat16 b = __float2bfloat16(f);
  return *reinterpret_cast<unsigned short*>(&b);
}
static __device__ __forceinline__ float bf2f(unsigned short u) {
  __hip_bfloat16 b = *reinterpret_cast<__hip_bfloat16*>(&u);
  return __bfloat162float(b);
}
static __device__ __forceinline__ float blo(unsigned int u) {
  return __uint_as_float(u << 16);
}
static __device__ __forceinline__ float bhi(unsigned int u) {
  return __uint_as_float(u & 0xffff0000u);
}

// ---------------- per-node logmap scale factors ----------------
__global__ __launch_bounds__(256) void k_scal(const float* __restrict__ xH,
                                              const float* __restrict__ xS,
                                              float* __restrict__ ch,
                                              float* __restrict__ cs) {
  int gw = (blockIdx.x * 256 + threadIdx.x) >> 6;
  int lane = threadIdx.x & 63;
  if (gw >= NN) return;
  const float2* h2 = (const float2*)(xH) + (size_t)gw * 64;
  float2 vh = h2[lane];
  float ssh = vh.x * vh.x + vh.y * vh.y;
  if (lane == 0) ssh -= vh.x * vh.x;
#pragma unroll
  for (int off = 32; off; off >>= 1) ssh += __shfl_down(ssh, off);
  const float2* s2 = (const float2*)(xS) + (size_t)gw * 64;
  float2 vs = s2[lane];
  float sss = vs.x * vs.x + vs.y * vs.y;
  if (lane == 0) sss -= vs.x * vs.x;
#pragma unroll
  for (int off = 32; off; off >>= 1) sss += __shfl_down(sss, off);
  if (lane == 0) {
    float nrh = sqrtf(ssh);
    float dist = acoshf(fmaxf(vh.x, 1.0f));
    ch[gw] = dist / fmaxf(nrh, 1e-12f);
    float nrs = sqrtf(sss);
    float th = acosf(fminf(fmaxf(vs.x, -1.0f), 1.0f));
    cs[gw] = th / fmaxf(nrs, 1e-12f);
  }
}

// ---------------- edge in-degree count ----------------
__global__ __launch_bounds__(256) void k_count(const int* __restrict__ dst,
                                               int* __restrict__ cnt) {
  int e = blockIdx.x * 256 + threadIdx.x;
  if (e < EE) atomicAdd(&cnt[dst[e]], 1);
}

// ---------------- hierarchical exclusive scan ----------------
__global__ __launch_bounds__(1024) void k_scan1(const int* __restrict__ cnt,
                                                int* __restrict__ rowstart,
                                                float* __restrict__ dinv,
                                                int* __restrict__ bsum) {
  __shared__ int wsum[16];
  int tid = threadIdx.x;
  int wave = tid >> 6, lane = tid & 63;
  int i = blockIdx.x * 1024 + tid;
  int v = (i < NN) ? cnt[i] : 0;
  int x = v;
#pragma unroll
  for (int off = 1; off < 64; off <<= 1) {
    int t = __shfl_up(x, off);
    if (lane >= off) x += t;
  }
  if (lane == 63) wsum[wave] = x;
  __syncthreads();
  if (wave == 0 && lane < 16) {
    int y = wsum[lane];
#pragma unroll
    for (int off = 1; off < 16; off <<= 1) {
      int t = __shfl_up(y, off);
      if (lane >= off) y += t;
    }
    wsum[lane] = y;
  }
  __syncthreads();
  int ex = (wave ? wsum[wave - 1] : 0) + x - v;
  if (i < NN) {
    rowstart[i] = ex;
    dinv[i] = 1.0f / sqrtf((float)(v + 1));
  }
  if (tid == 1023) bsum[blockIdx.x] = wsum[15];
}

__global__ __launch_bounds__(64) void k_scan2(int* __restrict__ bsum,
                                              int* __restrict__ rowstart,
                                              int nb) {
  int lane = threadIdx.x;
  int v = (lane < nb) ? bsum[lane] : 0;
  int x = v;
#pragma unroll
  for (int off = 1; off < 64; off <<= 1) {
    int t = __shfl_up(x, off);
    if (lane >= off) x += t;
  }
  if (lane < nb) bsum[lane] = x - v;
  if (lane == 0) rowstart[NN] = EE;
}

__global__ __launch_bounds__(1024) void k_scan3(int* __restrict__ rowstart,
                                                int* __restrict__ cursor,
                                                const int* __restrict__ bsum) {
  int i = blockIdx.x * 1024 + threadIdx.x;
  if (i < NN) {
    int r = rowstart[i] + bsum[blockIdx.x];
    rowstart[i] = r;
    cursor[i] = r;
  }
}

// ---------------- CSR placement ----------------
__global__ __launch_bounds__(256) void k_place(const int* __restrict__ src,
                                               const int* __restrict__ dst,
                                               int* __restrict__ cursor,
                                               int* __restrict__ col) {
  int e = blockIdx.x * 256 + threadIdx.x;
  if (e < EE) {
    int d = dst[e];
    int p = atomicAdd(&cursor[d], 1);
    col[p] = src[e];
  }
}

// ---------------- W transpose + bf16 hi/lo split: Wt[128][384] ----------------
__global__ __launch_bounds__(256) void k_wprep(const float* __restrict__ W,
                                               unsigned short* __restrict__ Wth,
                                               unsigned short* __restrict__ Wtl) {
  int flat = blockIdx.x * 256 + threadIdx.x;
  if (flat >= IND * DD) return;
  int n = flat / IND;
  int k = flat - n * IND;
  float v = W[(size_t)k * DD + n];
  unsigned short hi = f2bf(v);
  unsigned short lo = f2bf(v - bf2f(hi));
  Wth[(size_t)n * IND + k] = hi;
  Wtl[(size_t)n * IND + k] = lo;
}

// ---------------- MFMA GEMM: h = [xE | ch*xH | cs*xS] @ W, bf16 output ----
__global__ __launch_bounds__(256) void k_gemm(const float* __restrict__ xE,
                                              const float* __restrict__ xH,
                                              const float* __restrict__ xS,
                                              const float* __restrict__ ch,
                                              const float* __restrict__ cs,
                                              const unsigned short* __restrict__ Wth,
                                              const unsigned short* __restrict__ Wtl,
                                              unsigned short* __restrict__ h) {
  __shared__ unsigned short Ah[64 * 64];
  __shared__ unsigned short Al[64 * 64];
  int tid = threadIdx.x;
  int lane = tid & 63;
  int wid = tid >> 6;
  int wr = wid >> 1, wc = wid & 1;
  int r0 = wr * 32, c0 = wc * 64;
  int bm0 = blockIdx.x * 64;

  f4v acc[2][4];
#pragma unroll
  for (int m = 0; m < 2; ++m)
#pragma unroll
    for (int nf = 0; nf < 4; ++nf) acc[m][nf] = f4v{0.f, 0.f, 0.f, 0.f};

  int l15 = lane & 15;
  int lhi = lane >> 4;

  for (int kb = 0; kb < IND; kb += 64) {
    int sec = kb >> 7;
    int off = kb & 127;
    const float* src = (sec == 0) ? xE : (sec == 1) ? xH : xS;
#pragma unroll
    for (int it = 0; it < 4; ++it) {
      int flat = tid + it * 256;
      int row = flat >> 4;
      int f4 = flat & 15;
      int node = bm0 + row;
      float4 v = make_float4(0.f, 0.f, 0.f, 0.f);
      float scale = 0.f;
      if (node < NN) {
        v = *(const float4*)&src[(size_t)node * DD + off + f4 * 4];
        scale = (sec == 0) ? 1.0f : (sec == 1) ? ch[node] : cs[node];
      }
      v.x *= scale; v.y *= scale; v.z *= scale; v.w *= scale;
      if (sec > 0 && off == 0 && f4 == 0) v.x = 0.f;
      ushort4 hi, lo;
      hi.x = f2bf(v.x); lo.x = f2bf(v.x - bf2f(hi.x));
      hi.y = f2bf(v.y); lo.y = f2bf(v.y - bf2f(hi.y));
      hi.z = f2bf(v.z); lo.z = f2bf(v.z - bf2f(hi.z));
      hi.w = f2bf(v.w); lo.w = f2bf(v.w - bf2f(hi.w));
      int idx = (row * 64 + f4 * 4) ^ ((row & 7) << 3);
      *(ushort4*)&Ah[idx] = hi;
      *(ushort4*)&Al[idx] = lo;
    }
    __syncthreads();
#pragma unroll
    for (int ks = 0; ks < 2; ++ks) {
      s8v ahi[2], alo[2];
#pragma unroll
      for (int m = 0; m < 2; ++m) {
        int row = r0 + m * 16 + l15;
        int idx = (row * 64 + ks * 32 + lhi * 8) ^ ((row & 7) << 3);
        ahi[m] = *reinterpret_cast<const s8v*>(&Ah[idx]);
        alo[m] = *reinterpret_cast<const s8v*>(&Al[idx]);
      }
#pragma unroll
      for (int nf = 0; nf < 4; ++nf) {
        int n = c0 + nf * 16 + l15;
        int kk = kb + ks * 32 + lhi * 8;
        s8v bhi8 = *reinterpret_cast<const s8v*>(&Wth[(size_t)n * IND + kk]);
        s8v blo8 = *reinterpret_cast<const s8v*>(&Wtl[(size_t)n * IND + kk]);
#pragma unroll
        for (int m = 0; m < 2; ++m) {
          acc[m][nf] = __builtin_amdgcn_mfma_f32_16x16x32_bf16(ahi[m], bhi8, acc[m][nf], 0, 0, 0);
          acc[m][nf] = __builtin_amdgcn_mfma_f32_16x16x32_bf16(alo[m], bhi8, acc[m][nf], 0, 0, 0);
          acc[m][nf] = __builtin_amdgcn_mfma_f32_16x16x32_bf16(ahi[m], blo8, acc[m][nf], 0, 0, 0);
        }
      }
    }
    __syncthreads();
  }
#pragma unroll
  for (int m = 0; m < 2; ++m)
#pragma unroll
    for (int nf = 0; nf < 4; ++nf) {
      int colx = c0 + nf * 16 + l15;
      int rowb = bm0 + r0 + m * 16 + lhi * 4;
#pragma unroll
      for (int j = 0; j < 4; ++j) {
        int node = rowb + j;
        if (node < NN) h[(size_t)node * DD + colx] = f2bf(acc[m][nf][j]);
      }
    }
}

// ---------------- normalize class embeddings ----------------
__global__ __launch_bounds__(256) void k_clsn(const float* __restrict__ cls,
                                              float* __restrict__ clsn) {
  int wave = threadIdx.x >> 6, lane = threadIdx.x & 63;
  for (int c = wave; c < CC; c += 4) {
    const float2* r2 = (const float2*)(cls + (size_t)c * DD);
    float2 v = r2[lane];
    float ss = v.x * v.x + v.y * v.y;
#pragma unroll
    for (int off = 32; off; off >>= 1) ss += __shfl_down(ss, off);
    ss = __shfl(ss, 0);
    float inv = 1.0f / fmaxf(sqrtf(ss), 1e-8f);
    float2 o;
    o.x = v.x * inv;
    o.y = v.y * inv;
    ((float2*)(clsn + (size_t)c * DD))[lane] = o;
  }
}

// ---- fused CSR aggregation + row-normalize + classifier dot ----
__global__ __launch_bounds__(256) void k_aggout(const unsigned short* __restrict__ h,
                                                const int* __restrict__ rowstart,
                                                const int* __restrict__ col,
                                                const float* __restrict__ dinv,
                                                const float* __restrict__ b,
                                                const float* __restrict__ clsn,
                                                float* __restrict__ out) {
  __shared__ float4 cls4[CC * 32];
  __shared__ float4 xrow[4][32];
  int tid = threadIdx.x;
  for (int idx = tid; idx < CC * 32; idx += 256) {
    int c = idx >> 5, f4 = idx & 31;
    float4 v = ((const float4*)clsn)[c * 32 + f4];
    cls4[c * 32 + (f4 ^ (c & 7))] = v;
  }
  __syncthreads();
  int wave = tid >> 6, lane = tid & 63;
  int node = blockIdx.x * 4 + wave;
  if (node >= NN) return;

  const unsigned int* h2 = (const unsigned int*)h;  // 2 packed bf16 per uint
  float dv = dinv[node];
  unsigned int hv = h2[(size_t)node * 64 + lane];
  float ax = dv * blo(hv), ay = dv * bhi(hv);
  int s = rowstart[node], e = rowstart[node + 1];
  int j = s;
  for (; j + 7 < e; j += 8) {
    int c0_ = col[j], c1_ = col[j + 1], c2_ = col[j + 2], c3_ = col[j + 3];
    int c4_ = col[j + 4], c5_ = col[j + 5], c6_ = col[j + 6], c7_ = col[j + 7];
    float f0 = dinv[c0_], f1 = dinv[c1_], f2 = dinv[c2_], f3 = dinv[c3_];
    float f4_ = dinv[c4_], f5 = dinv[c5_], f6 = dinv[c6_], f7 = dinv[c7_];
    unsigned int v0 = h2[(size_t)c0_ * 64 + lane];
    unsigned int v1 = h2[(size_t)c1_ * 64 + lane];
    unsigned int v2 = h2[(size_t)c2_ * 64 + lane];
    unsigned int v3 = h2[(size_t)c3_ * 64 + lane];
    unsigned int v4 = h2[(size_t)c4_ * 64 + lane];
    unsigned int v5 = h2[(size_t)c5_ * 64 + lane];
    unsigned int v6 = h2[(size_t)c6_ * 64 + lane];
    unsigned int v7 = h2[(size_t)c7_ * 64 + lane];
    ax += f0 * blo(v0) + f1 * blo(v1) + f2 * blo(v2) + f3 * blo(v3);
    ay += f0 * bhi(v0) + f1 * bhi(v1) + f2 * bhi(v2) + f3 * bhi(v3);
    ax += f4_ * blo(v4) + f5 * blo(v5) + f6 * blo(v6) + f7 * blo(v7);
    ay += f4_ * bhi(v4) + f5 * bhi(v5) + f6 * bhi(v6) + f7 * bhi(v7);
  }
  for (; j < e; ++j) {
    int sc = col[j];
    float f = dinv[sc];
    unsigned int v = h2[(size_t)sc * 64 + lane];
    ax += f * blo(v);
    ay += f * bhi(v);
  }
  const float2* b2 = (const float2*)b;
  float2 bb = b2[lane];
  float rx = dv * ax + bb.x;
  float ry = dv * ay + bb.y;
  float ss = rx * rx + ry * ry;
#pragma unroll
  for (int off = 32; off; off >>= 1) ss += __shfl_xor(ss, off);
  float inv = 1.0f / fmaxf(sqrtf(ss), 1e-8f);
  float2 o;
  o.x = rx * inv;
  o.y = ry * inv;
  ((float2*)&xrow[wave][0])[lane] = o;
  float accv = 0.f;
  int c = lane;
#pragma unroll
  for (int f4 = 0; f4 < 32; ++f4) {
    float4 xv = xrow[wave][f4];
    float4 cv = cls4[c * 32 + (f4 ^ (c & 7))];
    accv += xv.x * cv.x + xv.y * cv.y + xv.z * cv.z + xv.w * cv.w;
  }
  out[(size_t)node * CC + c] = accv;
}

extern "C" void kernel_launch(void* const* d_in, const int* in_sizes, int n_in,
                              void* d_out, int out_size, void* d_ws, size_t ws_size,
                              hipStream_t stream) {
  const float* xE = (const float*)d_in[0];
  const float* xH = (const float*)d_in[1];
  const float* xS = (const float*)d_in[2];
  const int* ei = (const int*)d_in[3];
  const float* W = (const float*)d_in[4];
  const float* b = (const float*)d_in[5];
  const float* cls = (const float*)d_in[6];
  float* out = (float*)d_out;

  char* ws = (char*)d_ws;
  size_t off = 0;
  auto alloc = [&](size_t bytes) {
    void* p = ws + off;
    off = (off + bytes + 255) & ~(size_t)255;
    return p;
  };
  unsigned short* h = (unsigned short*)alloc((size_t)NN * DD * 2);
  float* dinv = (float*)alloc((size_t)NN * 4);
  float* chv = (float*)alloc((size_t)NN * 4);
  float* csv = (float*)alloc((size_t)NN * 4);
  int* cnt = (int*)alloc((size_t)NN * 4);
  int* rowst = (int*)alloc((size_t)(NN + 1) * 4);
  int* cursor = (int*)alloc((size_t)NN * 4);
  int* col = (int*)alloc((size_t)EE * 4);
  float* clsn = (float*)alloc((size_t)CC * DD * 4);
  unsigned short* Wth = (unsigned short*)alloc((size_t)DD * IND * 2);
  unsigned short* Wtl = (unsigned short*)alloc((size_t)DD * IND * 2);
  int* bsum = (int*)alloc(64 * 4);

  const int* esrc = ei;
  const int* edst = ei + EE;
  const int NB = (NN + 1023) / 1024;

  hipMemsetAsync(cnt, 0, (size_t)NN * 4, stream);
  k_scal<<<(NN + 3) / 4, 256, 0, stream>>>(xH, xS, chv, csv);
  k_count<<<(EE + 255) / 256, 256, 0, stream>>>(edst, cnt);
  k_scan1<<<NB, 1024, 0, stream>>>(cnt, rowst, dinv, bsum);
  k_scan2<<<1, 64, 0, stream>>>(bsum, rowst, NB);
  k_scan3<<<NB, 1024, 0, stream>>>(rowst, cursor, bsum);
  k_place<<<(EE + 255) / 256, 256, 0, stream>>>(esrc, edst, cursor, col);
  k_wprep<<<(IND * DD + 255) / 256, 256, 0, stream>>>(W, Wth, Wtl);
  k_gemm<<<(NN + 63) / 64, 256, 0, stream>>>(xE, xH, xS, chv, csv, Wth, Wtl, h);
  k_clsn<<<1, 256, 0, stream>>>(cls, clsn);
  k_aggout<<<(NN + 3) / 4, 256, 0, stream>>>(h, rowst, col, dinv, b, clsn, out);
}

// Round 4
// 253.936 us; speedup vs baseline: 2.1789x; 1.1286x over previous
//
#include <hip/hip_runtime.h>
#include <hip/hip_bf16.h>
#include <math.h>

#define NN 50000
#define DD 128
#define CC 64
#define EE 800000
#define IND 384

typedef __attribute__((ext_vector_type(8))) short s8v;
typedef __attribute__((ext_vector_type(4))) float f4v;

static __device__ __forceinline__ unsigned short f2bf(float f) {
  __hip_bfloat16 b = __float2bfloat16(f);
  return *reinterpret_cast<unsigned short*>(&b);
}
static __device__ __forceinline__ float bf2f(unsigned short u) {
  __hip_bfloat16 b = *reinterpret_cast<__hip_bfloat16*>(&u);
  return __bfloat162float(b);
}
static __device__ __forceinline__ float blo(unsigned int u) {
  return __uint_as_float(u << 16);
}
static __device__ __forceinline__ float bhi(unsigned int u) {
  return __uint_as_float(u & 0xffff0000u);
}
static __device__ __forceinline__ s8v zero8() {
  s8v v = {0, 0, 0, 0, 0, 0, 0, 0};
  return v;
}

// ---------------- per-node logmap scale factors ----------------
__global__ __launch_bounds__(256) void k_scal(const float* __restrict__ xH,
                                              const float* __restrict__ xS,
                                              float* __restrict__ ch,
                                              float* __restrict__ cs) {
  int gw = (blockIdx.x * 256 + threadIdx.x) >> 6;
  int lane = threadIdx.x & 63;
  if (gw >= NN) return;
  const float2* h2 = (const float2*)(xH) + (size_t)gw * 64;
  float2 vh = h2[lane];
  float ssh = vh.x * vh.x + vh.y * vh.y;
  if (lane == 0) ssh -= vh.x * vh.x;
#pragma unroll
  for (int off = 32; off; off >>= 1) ssh += __shfl_down(ssh, off);
  const float2* s2 = (const float2*)(xS) + (size_t)gw * 64;
  float2 vs = s2[lane];
  float sss = vs.x * vs.x + vs.y * vs.y;
  if (lane == 0) sss -= vs.x * vs.x;
#pragma unroll
  for (int off = 32; off; off >>= 1) sss += __shfl_down(sss, off);
  if (lane == 0) {
    float nrh = sqrtf(ssh);
    float dist = acoshf(fmaxf(vh.x, 1.0f));
    ch[gw] = dist / fmaxf(nrh, 1e-12f);
    float nrs = sqrtf(sss);
    float th = acosf(fminf(fmaxf(vs.x, -1.0f), 1.0f));
    cs[gw] = th / fmaxf(nrs, 1e-12f);
  }
}

// ---------------- edge in-degree count ----------------
__global__ __launch_bounds__(256) void k_count(const int* __restrict__ dst,
                                               int* __restrict__ cnt) {
  int e = blockIdx.x * 256 + threadIdx.x;
  if (e < EE) atomicAdd(&cnt[dst[e]], 1);
}

// ---------------- hierarchical exclusive scan ----------------
__global__ __launch_bounds__(1024) void k_scan1(const int* __restrict__ cnt,
                                                int* __restrict__ rowstart,
                                                float* __restrict__ dinv,
                                                int* __restrict__ bsum) {
  __shared__ int wsum[16];
  int tid = threadIdx.x;
  int wave = tid >> 6, lane = tid & 63;
  int i = blockIdx.x * 1024 + tid;
  int v = (i < NN) ? cnt[i] : 0;
  int x = v;
#pragma unroll
  for (int off = 1; off < 64; off <<= 1) {
    int t = __shfl_up(x, off);
    if (lane >= off) x += t;
  }
  if (lane == 63) wsum[wave] = x;
  __syncthreads();
  if (wave == 0 && lane < 16) {
    int y = wsum[lane];
#pragma unroll
    for (int off = 1; off < 16; off <<= 1) {
      int t = __shfl_up(y, off);
      if (lane >= off) y += t;
    }
    wsum[lane] = y;
  }
  __syncthreads();
  int ex = (wave ? wsum[wave - 1] : 0) + x - v;
  if (i < NN) {
    rowstart[i] = ex;
    dinv[i] = 1.0f / sqrtf((float)(v + 1));
  }
  if (tid == 1023) bsum[blockIdx.x] = wsum[15];
}

__global__ __launch_bounds__(64) void k_scan2(int* __restrict__ bsum,
                                              int* __restrict__ rowstart,
                                              int nb) {
  int lane = threadIdx.x;
  int v = (lane < nb) ? bsum[lane] : 0;
  int x = v;
#pragma unroll
  for (int off = 1; off < 64; off <<= 1) {
    int t = __shfl_up(x, off);
    if (lane >= off) x += t;
  }
  if (lane < nb) bsum[lane] = x - v;
  if (lane == 0) rowstart[NN] = EE;
}

__global__ __launch_bounds__(1024) void k_scan3(int* __restrict__ rowstart,
                                                int* __restrict__ cursor,
                                                const int* __restrict__ bsum) {
  int i = blockIdx.x * 1024 + threadIdx.x;
  if (i < NN) {
    int r = rowstart[i] + bsum[blockIdx.x];
    rowstart[i] = r;
    cursor[i] = r;
  }
}

// ---------------- CSR placement ----------------
__global__ __launch_bounds__(256) void k_place(const int* __restrict__ src,
                                               const int* __restrict__ dst,
                                               int* __restrict__ cursor,
                                               int* __restrict__ col) {
  int e = blockIdx.x * 256 + threadIdx.x;
  if (e < EE) {
    int d = dst[e];
    int p = atomicAdd(&cursor[d], 1);
    col[p] = src[e];
  }
}

// ---------------- W transpose + bf16 hi/lo split: Wt[128][384] ----------------
__global__ __launch_bounds__(256) void k_wprep(const float* __restrict__ W,
                                               unsigned short* __restrict__ Wth,
                                               unsigned short* __restrict__ Wtl) {
  int flat = blockIdx.x * 256 + threadIdx.x;
  if (flat >= IND * DD) return;
  int n = flat / IND;
  int k = flat - n * IND;
  float v = W[(size_t)k * DD + n];
  unsigned short hi = f2bf(v);
  unsigned short lo = f2bf(v - bf2f(hi));
  Wth[(size_t)n * IND + k] = hi;
  Wtl[(size_t)n * IND + k] = lo;
}

// ---------------- MFMA GEMM: h = [xE | ch*xH | cs*xS] @ W, bf16 output ----
__global__ __launch_bounds__(256) void k_gemm(const float* __restrict__ xE,
                                              const float* __restrict__ xH,
                                              const float* __restrict__ xS,
                                              const float* __restrict__ ch,
                                              const float* __restrict__ cs,
                                              const unsigned short* __restrict__ Wth,
                                              const unsigned short* __restrict__ Wtl,
                                              unsigned short* __restrict__ h) {
  __shared__ unsigned short Ah[64 * 64];
  __shared__ unsigned short Al[64 * 64];
  int tid = threadIdx.x;
  int lane = tid & 63;
  int wid = tid >> 6;
  int wr = wid >> 1, wc = wid & 1;
  int r0 = wr * 32, c0 = wc * 64;
  int bm0 = blockIdx.x * 64;

  f4v acc[2][4];
#pragma unroll
  for (int m = 0; m < 2; ++m)
#pragma unroll
    for (int nf = 0; nf < 4; ++nf) acc[m][nf] = f4v{0.f, 0.f, 0.f, 0.f};

  int l15 = lane & 15;
  int lhi = lane >> 4;

  for (int kb = 0; kb < IND; kb += 64) {
    int sec = kb >> 7;
    int off = kb & 127;
    const float* src = (sec == 0) ? xE : (sec == 1) ? xH : xS;
#pragma unroll
    for (int it = 0; it < 4; ++it) {
      int flat = tid + it * 256;
      int row = flat >> 4;
      int f4 = flat & 15;
      int node = bm0 + row;
      float4 v = make_float4(0.f, 0.f, 0.f, 0.f);
      float scale = 0.f;
      if (node < NN) {
        v = *(const float4*)&src[(size_t)node * DD + off + f4 * 4];
        scale = (sec == 0) ? 1.0f : (sec == 1) ? ch[node] : cs[node];
      }
      v.x *= scale; v.y *= scale; v.z *= scale; v.w *= scale;
      if (sec > 0 && off == 0 && f4 == 0) v.x = 0.f;
      ushort4 hi, lo;
      hi.x = f2bf(v.x); lo.x = f2bf(v.x - bf2f(hi.x));
      hi.y = f2bf(v.y); lo.y = f2bf(v.y - bf2f(hi.y));
      hi.z = f2bf(v.z); lo.z = f2bf(v.z - bf2f(hi.z));
      hi.w = f2bf(v.w); lo.w = f2bf(v.w - bf2f(hi.w));
      int idx = (row * 64 + f4 * 4) ^ ((row & 7) << 3);
      *(ushort4*)&Ah[idx] = hi;
      *(ushort4*)&Al[idx] = lo;
    }
    __syncthreads();
#pragma unroll
    for (int ks = 0; ks < 2; ++ks) {
      s8v ahi[2], alo[2];
#pragma unroll
      for (int m = 0; m < 2; ++m) {
        int row = r0 + m * 16 + l15;
        int idx = (row * 64 + ks * 32 + lhi * 8) ^ ((row & 7) << 3);
        ahi[m] = *reinterpret_cast<const s8v*>(&Ah[idx]);
        alo[m] = *reinterpret_cast<const s8v*>(&Al[idx]);
      }
#pragma unroll
      for (int nf = 0; nf < 4; ++nf) {
        int n = c0 + nf * 16 + l15;
        int kk = kb + ks * 32 + lhi * 8;
        s8v bhi8 = *reinterpret_cast<const s8v*>(&Wth[(size_t)n * IND + kk]);
        s8v blo8 = *reinterpret_cast<const s8v*>(&Wtl[(size_t)n * IND + kk]);
#pragma unroll
        for (int m = 0; m < 2; ++m) {
          acc[m][nf] = __builtin_amdgcn_mfma_f32_16x16x32_bf16(ahi[m], bhi8, acc[m][nf], 0, 0, 0);
          acc[m][nf] = __builtin_amdgcn_mfma_f32_16x16x32_bf16(alo[m], bhi8, acc[m][nf], 0, 0, 0);
          acc[m][nf] = __builtin_amdgcn_mfma_f32_16x16x32_bf16(ahi[m], blo8, acc[m][nf], 0, 0, 0);
        }
      }
    }
    __syncthreads();
  }
#pragma unroll
  for (int m = 0; m < 2; ++m)
#pragma unroll
    for (int nf = 0; nf < 4; ++nf) {
      int colx = c0 + nf * 16 + l15;
      int rowb = bm0 + r0 + m * 16 + lhi * 4;
#pragma unroll
      for (int j = 0; j < 4; ++j) {
        int node = rowb + j;
        if (node < NN) h[(size_t)node * DD + colx] = f2bf(acc[m][nf][j]);
      }
    }
}

// ---------------- normalize class embeddings -> bf16 hi/lo [64][128] ----------
__global__ __launch_bounds__(256) void k_cprep(const float* __restrict__ cls,
                                               unsigned int* __restrict__ clsh,
                                               unsigned int* __restrict__ clsl) {
  int wave = threadIdx.x >> 6, lane = threadIdx.x & 63;
  for (int c = wave; c < CC; c += 4) {
    const float2* r2 = (const float2*)(cls + (size_t)c * DD);
    float2 v = r2[lane];
    float ss = v.x * v.x + v.y * v.y;
#pragma unroll
    for (int off = 32; off; off >>= 1) ss += __shfl_xor(ss, off);
    float inv = 1.0f / fmaxf(sqrtf(ss), 1e-8f);
    float nx = v.x * inv, ny = v.y * inv;
    unsigned short hx = f2bf(nx), hy = f2bf(ny);
    unsigned short lx = f2bf(nx - bf2f(hx)), ly = f2bf(ny - bf2f(hy));
    clsh[c * 64 + lane] = (unsigned int)hx | ((unsigned int)hy << 16);
    clsl[c * 64 + lane] = (unsigned int)lx | ((unsigned int)ly << 16);
  }
}

// ---- CSR aggregation + in-wave normalize -> xn bf16 hi/lo ----
__global__ __launch_bounds__(256) void k_aggn(const unsigned short* __restrict__ h,
                                              const int* __restrict__ rowstart,
                                              const int* __restrict__ col,
                                              const float* __restrict__ dinv,
                                              const float* __restrict__ b,
                                              unsigned int* __restrict__ xnh,
                                              unsigned int* __restrict__ xnl) {
  int node = (blockIdx.x * 256 + threadIdx.x) >> 6;
  int lane = threadIdx.x & 63;
  if (node >= NN) return;

  const unsigned int* h2 = (const unsigned int*)h;
  float dv = dinv[node];
  unsigned int hv = h2[(size_t)node * 64 + lane];
  float ax = dv * blo(hv), ay = dv * bhi(hv);
  int s = rowstart[node], e = rowstart[node + 1];
  int j = s;
  for (; j + 7 < e; j += 8) {
    int c0_ = col[j], c1_ = col[j + 1], c2_ = col[j + 2], c3_ = col[j + 3];
    int c4_ = col[j + 4], c5_ = col[j + 5], c6_ = col[j + 6], c7_ = col[j + 7];
    float f0 = dinv[c0_], f1 = dinv[c1_], f2 = dinv[c2_], f3 = dinv[c3_];
    float f4_ = dinv[c4_], f5 = dinv[c5_], f6 = dinv[c6_], f7 = dinv[c7_];
    unsigned int v0 = h2[(size_t)c0_ * 64 + lane];
    unsigned int v1 = h2[(size_t)c1_ * 64 + lane];
    unsigned int v2 = h2[(size_t)c2_ * 64 + lane];
    unsigned int v3 = h2[(size_t)c3_ * 64 + lane];
    unsigned int v4 = h2[(size_t)c4_ * 64 + lane];
    unsigned int v5 = h2[(size_t)c5_ * 64 + lane];
    unsigned int v6 = h2[(size_t)c6_ * 64 + lane];
    unsigned int v7 = h2[(size_t)c7_ * 64 + lane];
    ax += f0 * blo(v0) + f1 * blo(v1) + f2 * blo(v2) + f3 * blo(v3);
    ay += f0 * bhi(v0) + f1 * bhi(v1) + f2 * bhi(v2) + f3 * bhi(v3);
    ax += f4_ * blo(v4) + f5 * blo(v5) + f6 * blo(v6) + f7 * blo(v7);
    ay += f4_ * bhi(v4) + f5 * bhi(v5) + f6 * bhi(v6) + f7 * bhi(v7);
  }
  for (; j < e; ++j) {
    int sc = col[j];
    float f = dinv[sc];
    unsigned int v = h2[(size_t)sc * 64 + lane];
    ax += f * blo(v);
    ay += f * bhi(v);
  }
  const float2* b2 = (const float2*)b;
  float2 bb = b2[lane];
  float rx = dv * ax + bb.x;
  float ry = dv * ay + bb.y;
  float ss = rx * rx + ry * ry;
#pragma unroll
  for (int off = 32; off; off >>= 1) ss += __shfl_xor(ss, off);
  float inv = 1.0f / fmaxf(sqrtf(ss), 1e-8f);
  float nx = rx * inv, ny = ry * inv;
  unsigned short hx = f2bf(nx), hy = f2bf(ny);
  unsigned short lx = f2bf(nx - bf2f(hx)), ly = f2bf(ny - bf2f(hy));
  xnh[(size_t)node * 64 + lane] = (unsigned int)hx | ((unsigned int)hy << 16);
  xnl[(size_t)node * 64 + lane] = (unsigned int)lx | ((unsigned int)ly << 16);
}

// ---- classifier MFMA GEMM: out = xn @ clsn^T (hi/lo 3-term) ----
__global__ __launch_bounds__(256) void k_outg(const unsigned short* __restrict__ xnh,
                                              const unsigned short* __restrict__ xnl,
                                              const unsigned short* __restrict__ clsh,
                                              const unsigned short* __restrict__ clsl,
                                              float* __restrict__ out) {
  int tid = threadIdx.x;
  int lane = tid & 63;
  int wid = tid >> 6;
  int l15 = lane & 15, lhi = lane >> 4;
  int bm0 = blockIdx.x * 128 + wid * 32;

  f4v acc[2][4];
#pragma unroll
  for (int m = 0; m < 2; ++m)
#pragma unroll
    for (int nf = 0; nf < 4; ++nf) acc[m][nf] = f4v{0.f, 0.f, 0.f, 0.f};

#pragma unroll
  for (int ks = 0; ks < 4; ++ks) {
    s8v ah[2], al[2];
#pragma unroll
    for (int m = 0; m < 2; ++m) {
      int row = bm0 + m * 16 + l15;
      if (row < NN) {
        ah[m] = *reinterpret_cast<const s8v*>(&xnh[(size_t)row * DD + ks * 32 + lhi * 8]);
        al[m] = *reinterpret_cast<const s8v*>(&xnl[(size_t)row * DD + ks * 32 + lhi * 8]);
      } else {
        ah[m] = zero8();
        al[m] = zero8();
      }
    }
#pragma unroll
    for (int nf = 0; nf < 4; ++nf) {
      int n = nf * 16 + l15;
      s8v bh = *reinterpret_cast<const s8v*>(&clsh[(size_t)n * DD + ks * 32 + lhi * 8]);
      s8v bl = *reinterpret_cast<const s8v*>(&clsl[(size_t)n * DD + ks * 32 + lhi * 8]);
#pragma unroll
      for (int m = 0; m < 2; ++m) {
        acc[m][nf] = __builtin_amdgcn_mfma_f32_16x16x32_bf16(ah[m], bh, acc[m][nf], 0, 0, 0);
        acc[m][nf] = __builtin_amdgcn_mfma_f32_16x16x32_bf16(al[m], bh, acc[m][nf], 0, 0, 0);
        acc[m][nf] = __builtin_amdgcn_mfma_f32_16x16x32_bf16(ah[m], bl, acc[m][nf], 0, 0, 0);
      }
    }
  }
#pragma unroll
  for (int m = 0; m < 2; ++m)
#pragma unroll
    for (int nf = 0; nf < 4; ++nf) {
      int colx = nf * 16 + l15;
      int rowb = bm0 + m * 16 + lhi * 4;
#pragma unroll
      for (int j = 0; j < 4; ++j) {
        int row = rowb + j;
        if (row < NN) out[(size_t)row * CC + colx] = acc[m][nf][j];
      }
    }
}

extern "C" void kernel_launch(void* const* d_in, const int* in_sizes, int n_in,
                              void* d_out, int out_size, void* d_ws, size_t ws_size,
                              hipStream_t stream) {
  const float* xE = (const float*)d_in[0];
  const float* xH = (const float*)d_in[1];
  const float* xS = (const float*)d_in[2];
  const int* ei = (const int*)d_in[3];
  const float* W = (const float*)d_in[4];
  const float* b = (const float*)d_in[5];
  const float* cls = (const float*)d_in[6];
  float* out = (float*)d_out;

  char* ws = (char*)d_ws;
  size_t off = 0;
  auto alloc = [&](size_t bytes) {
    void* p = ws + off;
    off = (off + bytes + 255) & ~(size_t)255;
    return p;
  };
  unsigned short* h = (unsigned short*)alloc((size_t)NN * DD * 2);
  unsigned int* xnh = (unsigned int*)alloc((size_t)NN * 64 * 4);
  unsigned int* xnl = (unsigned int*)alloc((size_t)NN * 64 * 4);
  float* dinv = (float*)alloc((size_t)NN * 4);
  float* chv = (float*)alloc((size_t)NN * 4);
  float* csv = (float*)alloc((size_t)NN * 4);
  int* cnt = (int*)alloc((size_t)NN * 4);
  int* rowst = (int*)alloc((size_t)(NN + 1) * 4);
  int* cursor = (int*)alloc((size_t)NN * 4);
  int* col = (int*)alloc((size_t)EE * 4);
  unsigned short* Wth = (unsigned short*)alloc((size_t)DD * IND * 2);
  unsigned short* Wtl = (unsigned short*)alloc((size_t)DD * IND * 2);
  unsigned int* clsh = (unsigned int*)alloc((size_t)CC * 64 * 4);
  unsigned int* clsl = (unsigned int*)alloc((size_t)CC * 64 * 4);
  int* bsum = (int*)alloc(64 * 4);

  const int* esrc = ei;
  const int* edst = ei + EE;
  const int NB = (NN + 1023) / 1024;

  hipMemsetAsync(cnt, 0, (size_t)NN * 4, stream);
  k_scal<<<(NN + 3) / 4, 256, 0, stream>>>(xH, xS, chv, csv);
  k_count<<<(EE + 255) / 256, 256, 0, stream>>>(edst, cnt);
  k_scan1<<<NB, 1024, 0, stream>>>(cnt, rowst, dinv, bsum);
  k_scan2<<<1, 64, 0, stream>>>(bsum, rowst, NB);
  k_scan3<<<NB, 1024, 0, stream>>>(rowst, cursor, bsum);
  k_place<<<(EE + 255) / 256, 256, 0, stream>>>(esrc, edst, cursor, col);
  k_wprep<<<(IND * DD + 255) / 256, 256, 0, stream>>>(W, Wth, Wtl);
  k_gemm<<<(NN + 63) / 64, 256, 0, stream>>>(xE, xH, xS, chv, csv, Wth, Wtl, h);
  k_cprep<<<1, 256, 0, stream>>>(cls, clsh, clsl);
  k_aggn<<<(NN + 3) / 4, 256, 0, stream>>>(h, rowst, col, dinv, b, xnh, xnl);
  k_outg<<<(NN + 127) / 128, 256, 0, stream>>>((const unsigned short*)xnh,
                                               (const unsigned short*)xnl,
                                               (const unsigned short*)clsh,
                                               (const unsigned short*)clsl, out);
}